// Round 10
// baseline (232.885 us; speedup 1.0000x reference)
//
#include <hip/hip_runtime.h>

// pol[g] = sum_{i in g} (q_i - mean(q)) * r_i = (sum_g q r) - mean * (sum_g r)
// Round 10: software-pipelined persistent waves. 1024 blocks x 256 thr =
// 4096 waves; each wave owns 4 tiles of 512 nodes (stride 4096) with ping-pong
// register buffers: reduce(T_i) always has tile T_{i+1}'s 8 float4 loads in
// flight (partial vmcnt waits, no full drain) — the m13-copy temporal shape.
// Reduce body / records / finalize = round-9 proven logic.

#define N_NODES     8388608
#define NUM_GRAPHS  1024
#define BLK         256
#define TILE_NODES  512                              // per wave-tile
#define NT          (N_NODES / TILE_NODES)           // 16384 tiles
#define G4T         (TILE_NODES / 4)                 // 128 float4 groups / tile
#define WAVES_TOT   4096                             // 1024 blocks * 4 waves
#define TPW         (NT / WAVES_TOT)                 // 4 tiles per wave

// ws layout (float offsets)
#define IBASE_OFF   16                               // int ibase[NT]
#define SPLIT_OFF   (IBASE_OFF + NT)                 // int4 split[NT]
#define REC_OFF     (SPLIT_OFF + 4 * NT)             // rec[NT][16]
#define REC_STRIDE  16
#define EXTRA_OFF   (REC_OFF + NT * REC_STRIDE)      // extra[NUM_GRAPHS][6]
#define WS_FLOATS   (EXTRA_OFF + NUM_GRAPHS * 6)     // 350224 floats = 1.4 MB

__global__ __launch_bounds__(BLK) void split_kernel(const int* __restrict__ batch,
                                                    float* __restrict__ ws) {
    int b = blockIdx.x * BLK + threadIdx.x;          // tile id, 0..NT-1
    if (b >= NT) return;
    if (b < 2048) {                                  // zero extra[]: 6144 floats
        float* extra = ws + EXTRA_OFF;
        extra[b * 3 + 0] = 0.f; extra[b * 3 + 1] = 0.f; extra[b * 3 + 2] = 0.f;
    }
    const int s = b * TILE_NODES;
    const int e = s + TILE_NODES;
    int i0 = batch[s];
    int i1 = batch[e - 1];
    int split = e;
    if (i1 != i0) {                                  // first idx in (s,e) with batch > i0
        int lo = s + 1, hi = e - 1;
        while (lo < hi) {
            int mid = (lo + hi) >> 1;
            if (batch[mid] > i0) hi = mid; else lo = mid + 1;
        }
        split = lo;
    }
    ((int4*)(ws + SPLIT_OFF))[b] = make_int4(i0, i1, split, 0);
    ((int*)(ws + IBASE_OFF))[b] = i0;
}

struct Buf { float4 Q[2], P0[2], P1[2], P2[2]; };

__global__ __launch_bounds__(BLK) void pol_main(const float4* __restrict__ p4,
                                                const float4* __restrict__ q4,
                                                const int*    __restrict__ batch,
                                                float* __restrict__ ws) {
    const int lane = threadIdx.x & 63;
    const int W    = blockIdx.x * 4 + (threadIdx.x >> 6);   // wave id, 0..4095
    float* extra = ws + EXTRA_OFF;
    const int4* sp4 = (const int4*)(ws + SPLIT_OFF);

    auto load_tile = [&](int T, Buf& B) {
        int vi0 = T * G4T;
        #pragma unroll
        for (int j = 0; j < 2; ++j) {
            int vi = vi0 + j * 64 + lane;
            B.Q[j]  = q4[vi];
            B.P0[j] = p4[3 * vi + 0];
            B.P1[j] = p4[3 * vi + 1];
            B.P2[j] = p4[3 * vi + 2];
        }
    };

    auto reduce_tile = [&](int T, int4 si, const Buf& Bf) {
        const int i0 = si.x, i1 = si.y, split = si.z;
        const bool general = (i1 > i0 + 1);          // impossible for this input
        float qsum = 0.f;
        float aqx = 0, aqy = 0, aqz = 0, arx = 0, ary = 0, arz = 0;
        float bqx = 0, bqy = 0, bqz = 0, brx = 0, bry = 0, brz = 0;

        if (!general) {
            #pragma unroll
            for (int j = 0; j < 2; ++j) {
                int n0 = (T * G4T + j * 64 + lane) * 4;
                float qs[4] = {Bf.Q[j].x, Bf.Q[j].y, Bf.Q[j].z, Bf.Q[j].w};
                float px[4] = {Bf.P0[j].x, Bf.P0[j].w, Bf.P1[j].z, Bf.P2[j].y};
                float py[4] = {Bf.P0[j].y, Bf.P1[j].x, Bf.P1[j].w, Bf.P2[j].z};
                float pz[4] = {Bf.P0[j].z, Bf.P1[j].y, Bf.P2[j].x, Bf.P2[j].w};
                qsum += (qs[0] + qs[1]) + (qs[2] + qs[3]);
                #pragma unroll
                for (int k = 0; k < 4; ++k) {
                    if (n0 + k < split) {            // pure tile: always true
                        aqx = fmaf(qs[k], px[k], aqx); aqy = fmaf(qs[k], py[k], aqy);
                        aqz = fmaf(qs[k], pz[k], aqz);
                        arx += px[k]; ary += py[k]; arz += pz[k];
                    } else {
                        bqx = fmaf(qs[k], px[k], bqx); bqy = fmaf(qs[k], py[k], bqy);
                        bqz = fmaf(qs[k], pz[k], bqz);
                        brx += px[k]; bry += py[k]; brz += pz[k];
                    }
                }
            }
        } else {  // never: per-node atomics into extra[], correct
            #pragma unroll
            for (int j = 0; j < 2; ++j) {
                int n0 = (T * G4T + j * 64 + lane) * 4;
                float qs[4] = {Bf.Q[j].x, Bf.Q[j].y, Bf.Q[j].z, Bf.Q[j].w};
                float px[4] = {Bf.P0[j].x, Bf.P0[j].w, Bf.P1[j].z, Bf.P2[j].y};
                float py[4] = {Bf.P0[j].y, Bf.P1[j].x, Bf.P1[j].w, Bf.P2[j].z};
                float pz[4] = {Bf.P0[j].z, Bf.P1[j].y, Bf.P2[j].x, Bf.P2[j].w};
                for (int k = 0; k < 4; ++k) {
                    int id = batch[n0 + k];
                    qsum += qs[k];
                    atomicAdd(&extra[id * 6 + 0], qs[k] * px[k]);
                    atomicAdd(&extra[id * 6 + 1], qs[k] * py[k]);
                    atomicAdd(&extra[id * 6 + 2], qs[k] * pz[k]);
                    atomicAdd(&extra[id * 6 + 3], px[k]);
                    atomicAdd(&extra[id * 6 + 4], py[k]);
                    atomicAdd(&extra[id * 6 + 5], pz[k]);
                }
            }
        }

        #pragma unroll
        for (int off = 32; off > 0; off >>= 1) {
            qsum += __shfl_down(qsum, off, 64);
            aqx += __shfl_down(aqx, off, 64); aqy += __shfl_down(aqy, off, 64);
            aqz += __shfl_down(aqz, off, 64); arx += __shfl_down(arx, off, 64);
            ary += __shfl_down(ary, off, 64); arz += __shfl_down(arz, off, 64);
        }
        if (i1 != i0 && !general) {
            #pragma unroll
            for (int off = 32; off > 0; off >>= 1) {
                bqx += __shfl_down(bqx, off, 64); bqy += __shfl_down(bqy, off, 64);
                bqz += __shfl_down(bqz, off, 64); brx += __shfl_down(brx, off, 64);
                bry += __shfl_down(bry, off, 64); brz += __shfl_down(brz, off, 64);
            }
        }
        if (lane == 0) {
            float* rec = ws + REC_OFF + (size_t)T * REC_STRIDE;
            rec[0] = qsum;
            rec[4] = aqx; rec[5] = aqy; rec[6] = aqz;
            rec[7] = arx; rec[8] = ary; rec[9] = arz;
            rec[10] = bqx; rec[11] = bqy; rec[12] = bqz;
            rec[13] = brx; rec[14] = bry; rec[15] = brz;
        }
    };

    const int T0 = W, T1 = W + WAVES_TOT, T2 = W + 2 * WAVES_TOT, T3 = W + 3 * WAVES_TOT;
    const int4 s0 = sp4[T0], s1 = sp4[T1], s2 = sp4[T2], s3 = sp4[T3];

    Buf A, B;
    load_tile(T0, A);
    load_tile(T1, B);
    reduce_tile(T0, s0, A);      // T1's 8 loads in flight during this
    load_tile(T2, A);
    reduce_tile(T1, s1, B);      // T2 in flight
    load_tile(T3, B);
    reduce_tile(T2, s2, A);      // T3 in flight
    reduce_tile(T3, s3, B);
}

// Single block, 1024 threads: mean from NT tile qsums, then per-graph gather:
// walk tiles touching g (i0<=g<=i1), add A if i0==g, B if i1==g (mixed).
__global__ __launch_bounds__(1024) void finalize_kernel(const float* __restrict__ ws,
                                                        float* __restrict__ out) {
    __shared__ float sm[16];
    __shared__ float smean;
    const int t = threadIdx.x;

    float s = 0.f;
    for (int i = t; i < NT; i += 1024) s += ws[REC_OFF + (size_t)i * REC_STRIDE];
    #pragma unroll
    for (int off = 32; off > 0; off >>= 1) s += __shfl_down(s, off, 64);
    if ((t & 63) == 0) sm[t >> 6] = s;
    __syncthreads();
    if (t == 0) {
        float tot = 0.f;
        #pragma unroll
        for (int i = 0; i < 16; ++i) tot += sm[i];
        smean = tot * (1.0f / (float)N_NODES);
    }
    __syncthreads();
    const float mean = smean;

    const int g = t;
    const int* ibase = (const int*)(ws + IBASE_OFF);
    const int4* sp4  = (const int4*)(ws + SPLIT_OFF);
    const float* extra = ws + EXTRA_OFF;

    float qx = extra[g * 6 + 0], qy = extra[g * 6 + 1], qz = extra[g * 6 + 2];
    float rx = extra[g * 6 + 3], ry = extra[g * 6 + 4], rz = extra[g * 6 + 5];

    int lo = 0, hi = NT - 1, B = -1;
    while (lo <= hi) {
        int mid = (lo + hi) >> 1;
        if (ibase[mid] <= g) { B = mid; lo = mid + 1; } else hi = mid - 1;
    }
    for (int b = B; b >= 0; --b) {
        int4 sb = sp4[b];
        if (sb.y < g) break;
        const float* r = ws + REC_OFF + (size_t)b * REC_STRIDE;
        if (sb.x == g) {
            qx += r[4]; qy += r[5]; qz += r[6];
            rx += r[7]; ry += r[8]; rz += r[9];
        }
        if (sb.y == g && sb.y != sb.x) {
            qx += r[10]; qy += r[11]; qz += r[12];
            rx += r[13]; ry += r[14]; rz += r[15];
        }
    }
    out[g * 3 + 0] = fmaf(-mean, rx, qx);
    out[g * 3 + 1] = fmaf(-mean, ry, qy);
    out[g * 3 + 2] = fmaf(-mean, rz, qz);
}

// ---------------- fallback path (round-1 code, known correct) ----------------

__global__ void sum_q_kernel(const float* __restrict__ q, float* __restrict__ ws, int n4) {
    int tid = blockIdx.x * blockDim.x + threadIdx.x;
    int stride = gridDim.x * blockDim.x;
    const float4* q4 = (const float4*)q;
    float s = 0.f;
    for (int i = tid; i < n4; i += stride) {
        float4 v = q4[i];
        s += (v.x + v.y) + (v.z + v.w);
    }
    for (int off = 32; off > 0; off >>= 1) s += __shfl_down(s, off, 64);
    __shared__ float smem[4];
    int lane = threadIdx.x & 63, wave = threadIdx.x >> 6;
    if (lane == 0) smem[wave] = s;
    __syncthreads();
    if (threadIdx.x == 0) atomicAdd(ws, (smem[0] + smem[1]) + (smem[2] + smem[3]));
}

__global__ void pol_atomic_kernel(const float* __restrict__ pos,
                                  const float* __restrict__ q,
                                  const int*   __restrict__ batch,
                                  const float* __restrict__ ws,
                                  float* __restrict__ out, int n) {
    const float mean = ws[0] * (1.0f / (float)N_NODES);
    int tid = blockIdx.x * blockDim.x + threadIdx.x;
    int stride = gridDim.x * blockDim.x;
    int n4 = n >> 2;
    const float4* q4 = (const float4*)q;
    const int4*   b4 = (const int4*)batch;
    const float4* p4 = (const float4*)pos;

    for (int i = tid; i < n4; i += stride) {
        float4 qv = q4[i];
        int4   bv = b4[i];
        float4 p0 = p4[3 * i + 0];
        float4 p1 = p4[3 * i + 1];
        float4 p2 = p4[3 * i + 2];
        float qs[4] = {qv.x - mean, qv.y - mean, qv.z - mean, qv.w - mean};
        int  ids[4] = {bv.x, bv.y, bv.z, bv.w};
        float px[4] = {p0.x, p0.w, p1.z, p2.y};
        float py[4] = {p0.y, p1.x, p1.w, p2.z};
        float pz[4] = {p0.z, p1.y, p2.x, p2.w};
        int cur = ids[0];
        float sx = 0.f, sy = 0.f, sz = 0.f;
        #pragma unroll
        for (int j = 0; j < 4; ++j) {
            if (ids[j] != cur) {
                atomicAdd(&out[cur * 3 + 0], sx);
                atomicAdd(&out[cur * 3 + 1], sy);
                atomicAdd(&out[cur * 3 + 2], sz);
                sx = sy = sz = 0.f;
                cur = ids[j];
            }
            sx = fmaf(qs[j], px[j], sx);
            sy = fmaf(qs[j], py[j], sy);
            sz = fmaf(qs[j], pz[j], sz);
        }
        int first = __shfl(cur, 0, 64);
        bool uniform = __all(cur == first);
        if (uniform) {
            for (int off = 32; off > 0; off >>= 1) {
                sx += __shfl_down(sx, off, 64);
                sy += __shfl_down(sy, off, 64);
                sz += __shfl_down(sz, off, 64);
            }
            if ((threadIdx.x & 63) == 0) {
                atomicAdd(&out[cur * 3 + 0], sx);
                atomicAdd(&out[cur * 3 + 1], sy);
                atomicAdd(&out[cur * 3 + 2], sz);
            }
        } else {
            atomicAdd(&out[cur * 3 + 0], sx);
            atomicAdd(&out[cur * 3 + 1], sy);
            atomicAdd(&out[cur * 3 + 2], sz);
        }
    }
}

extern "C" void kernel_launch(void* const* d_in, const int* in_sizes, int n_in,
                              void* d_out, int out_size, void* d_ws, size_t ws_size,
                              hipStream_t stream) {
    const float* pos   = (const float*)d_in[0];
    const float* q     = (const float*)d_in[1];
    const int*   batch = (const int*)d_in[2];
    float* out = (float*)d_out;
    float* ws  = (float*)d_ws;
    int n = in_sizes[1];

    if (ws_size >= (size_t)WS_FLOATS * sizeof(float)) {
        split_kernel<<<NT / BLK, BLK, 0, stream>>>(batch, ws);       // 64 blocks
        pol_main<<<WAVES_TOT / 4, BLK, 0, stream>>>((const float4*)pos,
                                                    (const float4*)q, batch, ws);
        finalize_kernel<<<1, 1024, 0, stream>>>(ws, out);
    } else {
        hipMemsetAsync(d_out, 0, (size_t)out_size * sizeof(float), stream);
        hipMemsetAsync(d_ws, 0, sizeof(float), stream);
        sum_q_kernel<<<4096, BLK, 0, stream>>>(q, ws, n >> 2);
        pol_atomic_kernel<<<8192, BLK, 0, stream>>>(pos, q, batch, ws, out, n);
    }
}